// Round 10
// baseline (247.123 us; speedup 1.0000x reference)
//
#include <hip/hip_runtime.h>

#define Bz   4
#define Nn   16384
#define Ss   4096
#define D1   128
#define D2   256
#define INCH 384
#define C0   256
#define C1   128
#define Mtot 65536
#define NCHUNK 16
#define SC    256   // sources per chunk

typedef unsigned short u16;
typedef unsigned int u32;
typedef unsigned long long u64;
typedef __attribute__((ext_vector_type(4))) float f32x4;
typedef __attribute__((ext_vector_type(8))) short bf16x8;
struct __align__(8) us4 { u16 x, y, z, w; };

__device__ __forceinline__ float bf2f(u16 u) {
  union { unsigned u; float f; } x; x.u = ((unsigned)u) << 16; return x.f;
}
__device__ __forceinline__ u16 f2bf(float f) {
  union { float f; unsigned u; } x; x.f = f;
  unsigned r = x.u + 0x7fffu + ((x.u >> 16) & 1u);
  return (u16)(r >> 16);
}
__device__ __forceinline__ u32 asu(float f) {
  union { float f; u32 u; } x; x.f = f; return x.u;
}
__device__ __forceinline__ float asf(u32 u) {
  union { u32 u; float f; } x; x.u = u; return x.f;
}
__device__ __forceinline__ void gload16(const void* g, void* l) {
  __builtin_amdgcn_global_load_lds(
      (const __attribute__((address_space(1))) unsigned*)g,
      (__attribute__((address_space(3))) unsigned*)l, 16, 0, 0);
}

// ---------------------------------------------------------------------------
// K1: partial top-3 per (query, source-chunk). Q=4 queries/thread.
// (key, idx) packed as u64 = (f32-bits(key) << 32) | idx, key = d^2 >= 0
// (clamped) so u64 order == lexicographic (key, index) EXACTLY. Top-3 is a
// min/max network; u64 min/max lowers to v_cmp_lt_u64 + 2 cndmask (all
// f32-rate) -- no DP pipe (r7's f64 min/max measured ~9 cyc each), no asm
// (r8/r9 failed to compile). Packed values unique -> stable-top_k ties.
// ---------------------------------------------------------------------------
#define QDECL(i) \
  float qx##i, qy##i, qz##i, n1##i; \
  u64 k0##i = ~0ull, k1##i = ~0ull, k2##i = ~0ull;

#define QLOAD(i) { \
  const float* p_ = xyz1 + ((size_t)qbase + i * 256 + t) * 3; \
  qx##i = p_[0]; qy##i = p_[1]; qz##i = p_[2]; \
  n1##i = qx##i*qx##i + qy##i*qy##i + qz##i*qz##i; }

#define EVAL(i, qv) { \
  float key_ = fmaf(qx##i, qv.x, fmaf(qy##i, qv.y, fmaf(qz##i, qv.z, qv.w))) + n1##i; \
  key_ = fmaxf(key_, 0.f); \
  up_.w[1] = asu(key_); \
  u64 u_ = up_.d; \
  bool g0_ = u_ < k0##i; \
  u64 hi_ = g0_ ? k0##i : u_; \
  k0##i   = g0_ ? u_ : k0##i; \
  bool g1_ = hi_ < k1##i; \
  u64 hi2_ = g1_ ? k1##i : hi_; \
  k1##i    = g1_ ? hi_ : k1##i; \
  k2##i = (hi2_ < k2##i) ? hi2_ : k2##i; }

#define EVALS(qv, idxv) { \
  union { u64 d; u32 w[2]; } up_; \
  up_.w[0] = (idxv); \
  EVAL(0, qv) EVAL(1, qv) EVAL(2, qv) EVAL(3, qv) }

#define QSTORE(i) { \
  size_t q_ = (size_t)qbase + i * 256 + t; \
  pkey[(size_t)(chunk*3 + 0) * Mtot + q_] = k0##i; \
  pkey[(size_t)(chunk*3 + 1) * Mtot + q_] = k1##i; \
  pkey[(size_t)(chunk*3 + 2) * Mtot + q_] = k2##i; }

__global__ __launch_bounds__(256, 4) void knn_partial(
    const float* __restrict__ xyz1, const float* __restrict__ xyz2,
    u64* __restrict__ pkey)
{
  __shared__ float4 s_q[SC];
  const int t     = threadIdx.x;
  const int chunk = blockIdx.x & (NCHUNK - 1);
  const int qb    = blockIdx.x >> 4;         // 0..63
  const int b     = qb >> 4;                 // batch (16 q-blocks per batch)
  const int qbase = qb << 10;                // 1024 queries per q-block

  {
    const float* src = xyz2 + ((size_t)b * Ss + chunk * SC + t) * 3;
    float x = src[0], y = src[1], z = src[2];
    s_q[t] = make_float4(-2.f * x, -2.f * y, -2.f * z, x*x + y*y + z*z);
  }
  QDECL(0) QDECL(1) QDECL(2) QDECL(3)
  QLOAD(0) QLOAD(1) QLOAD(2) QLOAD(3)
  __syncthreads();

  u32 sidx = (u32)(chunk * SC);
  for (int j = 0; j < SC; j += 4) {
    float4 qa  = s_q[j + 0];
    float4 qb_ = s_q[j + 1];
    float4 qc  = s_q[j + 2];
    float4 qd  = s_q[j + 3];
    EVALS(qa,  sidx)
    EVALS(qb_, sidx + 1)
    EVALS(qc,  sidx + 2)
    EVALS(qd,  sidx + 3)
    sidx += 4;
  }
  QSTORE(0) QSTORE(1) QSTORE(2) QSTORE(3)
}

// ---------------------------------------------------------------------------
// K2: merge 16 partials -> top-3, weights, gather points2, concat -> Xb bf16
// 1024 blocks x 256 threads; 64 queries per block.
// ---------------------------------------------------------------------------
__global__ __launch_bounds__(256) void knn_merge_interp(
    const float* __restrict__ points1, const float* __restrict__ points2,
    const u64* __restrict__ pkey, u16* __restrict__ Xb)
{
  __shared__ int   s_i[64][3];
  __shared__ float s_w[64][3];
  const int t = threadIdx.x;
  const size_t qbase = (size_t)blockIdx.x * 64;
  const int b = (int)(qbase >> 14);

  if (t < 64) {
    size_t q = qbase + t;
    u64 k0 = ~0ull, k1 = ~0ull, k2 = ~0ull;
    #pragma unroll 4
    for (int c = 0; c < NCHUNK * 3; ++c) {
      u64 u = pkey[(size_t)c * Mtot + q];
      bool g0 = u < k0;
      u64 hi = g0 ? k0 : u;
      k0     = g0 ? u  : k0;
      bool g1 = hi < k1;
      u64 hi2 = g1 ? k1 : hi;
      k1      = g1 ? hi : k1;
      k2 = (hi2 < k2) ? hi2 : k2;
    }
    float d0 = asf((u32)(k0 >> 32));
    float d1 = asf((u32)(k1 >> 32));
    float d2 = asf((u32)(k2 >> 32));
    float r0 = 1.f / (d0 + 1e-8f);
    float r1 = 1.f / (d1 + 1e-8f);
    float r2 = 1.f / (d2 + 1e-8f);
    float rs = 1.f / (r0 + r1 + r2);
    s_i[t][0] = (int)(u32)k0;
    s_i[t][1] = (int)(u32)k1;
    s_i[t][2] = (int)(u32)k2;
    s_w[t][0] = r0 * rs; s_w[t][1] = r1 * rs; s_w[t][2] = r2 * rs;
  }
  __syncthreads();

  // points1 -> Xb[:, 0:128]
  const float* p1 = points1 + qbase * D1;
  u16* xr = Xb + qbase * INCH;
  #pragma unroll
  for (int k = 0; k < 8; ++k) {
    int i = k * 256 + t;
    int r = i >> 5, c4 = (i & 31) << 2;
    float4 v = *(const float4*)(p1 + (size_t)r * D1 + c4);
    us4 o = { f2bf(v.x), f2bf(v.y), f2bf(v.z), f2bf(v.w) };
    *(us4*)(xr + (size_t)r * INCH + c4) = o;
  }
  // interp -> Xb[:, 128:384]
  const float* p2 = points2 + (size_t)b * Ss * D2;
  const int sub = t >> 6, cg = (t & 63) << 2;
  #pragma unroll 2
  for (int pass = 0; pass < 16; ++pass) {
    int p = pass * 4 + sub;
    int i0 = s_i[p][0], i1 = s_i[p][1], i2 = s_i[p][2];
    float w0 = s_w[p][0], w1 = s_w[p][1], w2 = s_w[p][2];
    float4 f0 = *(const float4*)(p2 + (size_t)i0 * D2 + cg);
    float4 f1 = *(const float4*)(p2 + (size_t)i1 * D2 + cg);
    float4 f2 = *(const float4*)(p2 + (size_t)i2 * D2 + cg);
    float v0 = w0*f0.x + w1*f1.x + w2*f2.x;
    float v1 = w0*f0.y + w1*f1.y + w2*f2.y;
    float v2 = w0*f0.z + w1*f1.z + w2*f2.z;
    float v3 = w0*f0.w + w1*f1.w + w2*f2.w;
    us4 o = { f2bf(v0), f2bf(v1), f2bf(v2), f2bf(v3) };
    *(us4*)(xr + (size_t)p * INCH + D1 + cg) = o;
  }
}

// ---------------------------------------------------------------------------
// fp32 -> bf16 conversion of both weight matrices in one launch
// ---------------------------------------------------------------------------
__global__ __launch_bounds__(256) void cvt_weights_kernel(
    const float* __restrict__ w0s, u16* __restrict__ w0d,
    const float* __restrict__ w1s, u16* __restrict__ w1d)
{
  int i = blockIdx.x * 256 + threadIdx.x;
  const int n0 = C0 * INCH / 4;             // 24576
  const int n1 = C1 * C0 / 4;               // 8192
  if (i < n0) {
    float4 v = *(const float4*)(w0s + (size_t)i * 4);
    us4 o = { f2bf(v.x), f2bf(v.y), f2bf(v.z), f2bf(v.w) };
    *(us4*)(w0d + (size_t)i * 4) = o;
  } else if (i - n0 < n1) {
    int k = i - n0;
    float4 v = *(const float4*)(w1s + (size_t)k * 4);
    us4 o = { f2bf(v.x), f2bf(v.y), f2bf(v.z), f2bf(v.w) };
    *(us4*)(w1d + (size_t)k * 4) = o;
  }
}

// per-pair transform: relu(a*x+b) on two packed bf16
__device__ __forceinline__ u32 nr2(u32 two, float aL, float bL, float aH, float bH) {
  float lo = fmaxf(0.f, fmaf(bf2f((u16)(two & 0xffff)), aL, bL));
  float hi = fmaxf(0.f, fmaf(bf2f((u16)(two >> 16)),    aH, bH));
  return (u32)f2bf(lo) | ((u32)f2bf(hi) << 16);
}

// ---------------------------------------------------------------------------
// MFMA GEMM: out[M][NOUT] = X[M][K](bf16) * Wb[NOUT][K](bf16)^T + bias
// 128x128 tile, BK=64, 4 waves (2x2 of 64x64), 16x16x32 bf16 MFMA.
// ATRANS: A staged via registers with fused relu(a*x+b) channel transform
//   (ds_write to XOR-swizzled dest; same involution on read - rule 21).
// !ATRANS: A staged via global_load_lds with inverse-swizzled source.
// Epilogue: fused BN column stats (s, s^2) -> Spart/SQpart[512 slots][NOUT],
//   two row-half waves combined through LDS; fully deterministic.
// ---------------------------------------------------------------------------
template<int K, int NOUT, bool OUT_BF16, bool ATRANS>
__global__ __launch_bounds__(256) void gemm_mfma(
    const u16* __restrict__ X, const u16* __restrict__ Wb,
    const float* __restrict__ bias, const float* __restrict__ ABt,
    void* __restrict__ out, float* __restrict__ Spart, float* __restrict__ SQpart)
{
  __shared__ u16 ldsA[128 * 64];
  __shared__ u16 ldsB[128 * 64];
  const int t = threadIdx.x;
  const int w = t >> 6, lane = t & 63;
  const int m0 = blockIdx.y * 128, n0 = blockIdx.x * 128;
  const int wm = (w >> 1) * 64, wn = (w & 1) * 64;

  f32x4 acc[4][4];
  #pragma unroll
  for (int mi = 0; mi < 4; ++mi)
    #pragma unroll
    for (int ni = 0; ni < 4; ++ni)
      acc[mi][ni] = (f32x4){0.f, 0.f, 0.f, 0.f};

  // staging descriptors: chunk ci covers LDS bytes [(ci*256+t)*16, +16)
  const char* aS[4]; const char* bS[4];   // !ATRANS path (inverse-swz source)
  const u16* aRow[4]; char* aDst[4]; int abk[4];  // ATRANS path
  #pragma unroll
  for (int ci = 0; ci < 4; ++ci) {
    int d  = (ci * 256 + t) * 16;
    int r  = d >> 7;                 // row 0..127
    int cb = d & 127;                // byte-in-row
    int cbs = cb ^ ((r & 7) << 4);   // inverse swizzle on SOURCE
    bS[ci] = (const char*)(Wb + (size_t)(n0 + r) * K) + cbs;
    if constexpr (ATRANS) {
      aRow[ci] = X + (size_t)(m0 + r) * K + (cb >> 1);
      aDst[ci] = (char*)ldsA + (d ^ ((r & 7) << 4));
      abk[ci]  = cb >> 1;
    } else {
      aS[ci] = (const char*)(X + (size_t)(m0 + r) * K) + cbs;
    }
  }

  for (int kt = 0; kt < K / 64; ++kt) {
    __syncthreads();                 // previous tile consumed
    #pragma unroll
    for (int ci = 0; ci < 4; ++ci)
      gload16(bS[ci] + kt * 128, (char*)ldsB + (ci * 256 + w * 64) * 16);
    if constexpr (ATRANS) {
      #pragma unroll
      for (int ci = 0; ci < 4; ++ci) {
        uint4 xv = *(const uint4*)(aRow[ci] + kt * 64);
        int k0 = kt * 64 + abk[ci];
        float4 a0 = *(const float4*)(ABt + k0);
        float4 a1 = *(const float4*)(ABt + k0 + 4);
        float4 b0 = *(const float4*)(ABt + K + k0);
        float4 b1 = *(const float4*)(ABt + K + k0 + 4);
        uint4 ov;
        ov.x = nr2(xv.x, a0.x, b0.x, a0.y, b0.y);
        ov.y = nr2(xv.y, a0.z, b0.z, a0.w, b0.w);
        ov.z = nr2(xv.z, a1.x, b1.x, a1.y, b1.y);
        ov.w = nr2(xv.w, a1.z, b1.z, a1.w, b1.w);
        *(uint4*)aDst[ci] = ov;
      }
    } else {
      #pragma unroll
      for (int ci = 0; ci < 4; ++ci)
        gload16(aS[ci] + kt * 128, (char*)ldsA + (ci * 256 + w * 64) * 16);
    }
    __syncthreads();                 // compiler drains vmcnt+lgkmcnt
    #pragma unroll
    for (int ks = 0; ks < 2; ++ks) {
      bf16x8 a[4], bfr[4];
      const int ka = ks * 64 + ((lane >> 4) << 4);
      #pragma unroll
      for (int x = 0; x < 4; ++x) {
        int ra = wm + x * 16 + (lane & 15);
        a[x]   = *(const bf16x8*)((const char*)ldsA + ra * 128 + (ka ^ ((ra & 7) << 4)));
        int rb = wn + x * 16 + (lane & 15);
        bfr[x] = *(const bf16x8*)((const char*)ldsB + rb * 128 + (ka ^ ((rb & 7) << 4)));
      }
      #pragma unroll
      for (int mi = 0; mi < 4; ++mi)
        #pragma unroll
        for (int ni = 0; ni < 4; ++ni)
          acc[mi][ni] = __builtin_amdgcn_mfma_f32_16x16x32_bf16(
              a[mi], bfr[ni], acc[mi][ni], 0, 0, 0);
    }
  }

  // epilogue: C/D layout col=lane&15, row=(lane>>4)*4+reg (m89-verified)
  // + fused BN column stats (sum, sumsq of v = acc + bias, fp32 pre-rounding)
  __syncthreads();                   // LDS free -> reuse for stat combine
  float* redS  = (float*)ldsA;       // [128] local cols
  float* redSQ = redS + 128;
  const int col = lane & 15;
  const int rg  = (lane >> 4) << 2;
  float sv[4], qv[4];
  #pragma unroll
  for (int ni = 0; ni < 4; ++ni) {
    int c = n0 + wn + ni * 16 + col;
    float bb = bias[c];
    float s = 0.f, sq = 0.f;
    #pragma unroll
    for (int mi = 0; mi < 4; ++mi) {
      int rbase = m0 + wm + mi * 16 + rg;
      #pragma unroll
      for (int rr = 0; rr < 4; ++rr) {
        float v = acc[mi][ni][rr] + bb;
        s += v; sq = fmaf(v, v, sq);
        if constexpr (OUT_BF16)
          ((u16*)out)[(size_t)(rbase + rr) * NOUT + c] = f2bf(v);
        else
          ((float*)out)[(size_t)(rbase + rr) * NOUT + c] = v;
      }
    }
    s  += __shfl_xor(s, 16, 64);  s  += __shfl_xor(s, 32, 64);
    sq += __shfl_xor(sq, 16, 64); sq += __shfl_xor(sq, 32, 64);
    sv[ni] = s; qv[ni] = sq;
  }
  if ((w >> 1) == 1 && lane < 16) {
    #pragma unroll
    for (int ni = 0; ni < 4; ++ni) {
      redS [wn + ni * 16 + col] = sv[ni];
      redSQ[wn + ni * 16 + col] = qv[ni];
    }
  }
  __syncthreads();
  if ((w >> 1) == 0 && lane < 16) {
    #pragma unroll
    for (int ni = 0; ni < 4; ++ni) {
      int cl = wn + ni * 16 + col;
      Spart [(size_t)blockIdx.y * NOUT + n0 + cl] = sv[ni] + redS[cl];
      SQpart[(size_t)blockIdx.y * NOUT + n0 + cl] = qv[ni] + redSQ[cl];
    }
  }
}

// ---------------------------------------------------------------------------
// stats finish: grid = C blocks x 256 threads; reduce nslot partial slots,
// fold (mean, rstd, gamma, beta) -> per-channel (a, b).
// ---------------------------------------------------------------------------
__global__ __launch_bounds__(256) void stats_finish(
    const float* __restrict__ Spart, const float* __restrict__ SQpart,
    const float* __restrict__ gamma, const float* __restrict__ beta,
    float* __restrict__ AB, int nslot)
{
  const int C = gridDim.x, c = blockIdx.x, i = threadIdx.x;
  float s = 0.f, sq = 0.f;
  for (int k = i; k < nslot; k += 256) {
    s  += Spart [(size_t)k * C + c];
    sq += SQpart[(size_t)k * C + c];
  }
  #pragma unroll
  for (int d = 32; d; d >>= 1) {
    s  += __shfl_down(s, d, 64);
    sq += __shfl_down(sq, d, 64);
  }
  __shared__ float ls[4], lq[4];
  int w = i >> 6, lane = i & 63;
  if (lane == 0) { ls[w] = s; lq[w] = sq; }
  __syncthreads();
  if (i == 0) {
    s  = ls[0] + ls[1] + ls[2] + ls[3];
    sq = lq[0] + lq[1] + lq[2] + lq[3];
    const float inv = 1.0f / (float)Mtot;
    float mean = s * inv;
    float var  = fmaf(-mean, mean, sq * inv);
    float a = rsqrtf(var + 1e-5f) * gamma[c];
    AB[c]     = a;
    AB[C + c] = fmaf(-mean, a, beta[c]);
  }
}

__global__ __launch_bounds__(256) void norm_relu_f32(float* __restrict__ Y,
                                                     const float* __restrict__ AB)
{
  size_t g = (size_t)blockIdx.x * 256 + threadIdx.x;  // 4 f32 per thread
  float* p = Y + g * 4;
  int c0 = (int)((g * 4) & (C1 - 1));
  float4 v = *(const float4*)p;
  float4 a = *(const float4*)(AB + c0);
  float4 b = *(const float4*)(AB + C1 + c0);
  v.x = fmaxf(0.f, fmaf(v.x, a.x, b.x));
  v.y = fmaxf(0.f, fmaf(v.y, a.y, b.y));
  v.z = fmaxf(0.f, fmaf(v.z, a.z, b.z));
  v.w = fmaxf(0.f, fmaf(v.w, a.w, b.w));
  *(float4*)p = v;
}

// ---------------------------------------------------------------------------
extern "C" void kernel_launch(void* const* d_in, const int* in_sizes, int n_in,
                              void* d_out, int out_size, void* d_ws, size_t ws_size,
                              hipStream_t stream) {
  const float* xyz1    = (const float*)d_in[0];
  const float* xyz2    = (const float*)d_in[1];
  const float* points1 = (const float*)d_in[2];
  const float* points2 = (const float*)d_in[3];
  const float* w0  = (const float*)d_in[4];
  const float* b0  = (const float*)d_in[5];
  const float* g0  = (const float*)d_in[6];
  const float* be0 = (const float*)d_in[7];
  const float* w1  = (const float*)d_in[8];
  const float* b1  = (const float*)d_in[9];
  const float* g1  = (const float*)d_in[10];
  const float* be1 = (const float*)d_in[11];
  float* out = (float*)d_out;
  char* ws = (char*)d_ws;

  const size_t XB_OFF  = 0;                               // 50,331,648
  const size_t Y1_OFF  = (size_t)Mtot * INCH * 2;         // 33,554,432 (Y1)
  // K1 partials (u64, 25.2 MB) overlay Y1 (dead before GEMM1 writes Y1):
  const size_t PKEY_OFF = Y1_OFF;
  const size_t SP_OFF  = Y1_OFF + (size_t)Mtot * C0 * 2;  // 512x256 f32
  const size_t SQ_OFF  = SP_OFF + (size_t)512 * C0 * 4;
  const size_t AB0_OFF = SQ_OFF + (size_t)512 * C0 * 4;
  const size_t AB1_OFF = AB0_OFF + 2048;
  const size_t WB0_OFF = AB1_OFF + 2048;
  const size_t WB1_OFF = WB0_OFF + (size_t)C0 * INCH * 2;

  u16*   Xb   = (u16*)(ws + XB_OFF);
  u16*   Y1   = (u16*)(ws + Y1_OFF);
  u64*   pkey = (u64*)(ws + PKEY_OFF);
  float* SP   = (float*)(ws + SP_OFF);   // reused by both GEMMs (sequential)
  float* SQ   = (float*)(ws + SQ_OFF);
  float* AB0  = (float*)(ws + AB0_OFF);
  float* AB1  = (float*)(ws + AB1_OFF);
  u16*   Wb0  = (u16*)(ws + WB0_OFF);
  u16*   Wb1  = (u16*)(ws + WB1_OFF);

  // 0) weights -> bf16
  cvt_weights_kernel<<<dim3(128), dim3(256), 0, stream>>>(w0, Wb0, w1, Wb1);
  // 1) KNN partial top-3 (u64 lex (key,idx) min/max network)
  knn_partial<<<dim3(64 * NCHUNK), dim3(256), 0, stream>>>(xyz1, xyz2, pkey);
  // 2) merge + interpolate + concat -> Xb
  knn_merge_interp<<<dim3(Mtot / 64), dim3(256), 0, stream>>>(
      points1, points2, pkey, Xb);
  // 3) GEMM1 + fused BN0 column stats: [M,384]x[384,256]^T -> Y1 raw bf16
  gemm_mfma<INCH, C0, true, false>
      <<<dim3(C0 / 128, Mtot / 128), dim3(256), 0, stream>>>(
      Xb, Wb0, b0, nullptr, (void*)Y1, SP, SQ);
  // 4) BN0 fold
  stats_finish<<<dim3(C0), dim3(256), 0, stream>>>(SP, SQ, g0, be0, AB0, 512);
  // 5) GEMM2 (A-staging applies relu(a*x+b)) + fused BN1 stats -> d_out raw f32
  gemm_mfma<C0, C1, false, true>
      <<<dim3(C1 / 128, Mtot / 128), dim3(256), 0, stream>>>(
      Y1, Wb1, b1, AB0, (void*)out, SP, SQ);
  // 6) BN1 fold
  stats_finish<<<dim3(C1), dim3(256), 0, stream>>>(SP, SQ, g1, be1, AB1, 512);
  // 7) normalize + relu d_out in place
  norm_relu_f32<<<dim3(Mtot * C1 / 4 / 256), dim3(256), 0, stream>>>(out, AB1);
}

// Round 11
// 185.173 us; speedup vs baseline: 1.3346x; 1.3346x over previous
//
#include <hip/hip_runtime.h>

#define Bz   4
#define Nn   16384
#define Ss   4096
#define D1   128
#define D2   256
#define INCH 384
#define C0   256
#define C1   128
#define Mtot 65536
#define NCHUNK 16
#define SC    256   // sources per chunk

typedef unsigned short u16;
typedef unsigned int u32;
typedef __attribute__((ext_vector_type(4))) float f32x4;
typedef __attribute__((ext_vector_type(8))) short bf16x8;
struct __align__(8) us4 { u16 x, y, z, w; };

__device__ __forceinline__ float bf2f(u16 u) {
  union { unsigned u; float f; } x; x.u = ((unsigned)u) << 16; return x.f;
}
__device__ __forceinline__ u16 f2bf(float f) {
  union { float f; unsigned u; } x; x.f = f;
  unsigned r = x.u + 0x7fffu + ((x.u >> 16) & 1u);
  return (u16)(r >> 16);
}
__device__ __forceinline__ u32 asu(float f) {
  union { float f; u32 u; } x; x.f = f; return x.u;
}
__device__ __forceinline__ u32 pk_idx(double d) {
  union { double d; u32 u[2]; } x; x.d = d; return x.u[0];
}
__device__ __forceinline__ float pk_key(double d) {
  union { double d; u32 u[2]; } x; x.d = d;
  union { u32 u; float f; } y; y.u = x.u[1]; return y.f;
}
__device__ __forceinline__ double pk(float key, u32 idx) {
  union { double d; u32 u[2]; } x;
  x.u[0] = idx; x.u[1] = asu(key);
  return x.d;
}
__device__ __forceinline__ void gload16(const void* g, void* l) {
  __builtin_amdgcn_global_load_lds(
      (const __attribute__((address_space(1))) unsigned*)g,
      (__attribute__((address_space(3))) unsigned*)l, 16, 0, 0);
}

// ---------------------------------------------------------------------------
// K1: partial top-3 per (query, source-chunk). Q=4 queries/thread.
// key = |s|^2 - 2<q,s>  (EXACT fp32; monotone in sq-dist, n1 added at merge).
// (key,idx) packed as f64 -> 5-op v_min/max_f64 sorting network. Measured
// 53.6 cyc/eval (r7) -- the cheapest compiler-reachable EXACT insert:
// u64 ternaries bloat 2.5x (r10: 91.5 cyc), f32+cndmask C++ is 62 cyc (r4),
// hand asm fails to compile (r8/r9). Exact index tracking is mandatory:
// key-match recovery would hit ~2.4 exact-f32 boundary ties over the dataset.
// ---------------------------------------------------------------------------
#define QDECL(i) \
  float qx##i, qy##i, qz##i; \
  double k0##i, k1##i, k2##i;

#define QINIT(i) { \
  k0##i = pk(3.3e38f, 0xFFFFFFFFu); \
  k1##i = k0##i; k2##i = k0##i; }

#define QLOAD(i) { \
  const float* p_ = xyz1 + ((size_t)qbase + i * 256 + t) * 3; \
  qx##i = p_[0]; qy##i = p_[1]; qz##i = p_[2]; }

#define EVAL1(i, qv, up) { \
  up.u[1] = asu(fmaf(qx##i, qv.x, fmaf(qy##i, qv.y, fmaf(qz##i, qv.z, qv.w)))); \
  double u_ = up.d; \
  double hi_  = fmax(k0##i, u_); k0##i = fmin(k0##i, u_); \
  double hi2_ = fmax(k1##i, hi_); k1##i = fmin(k1##i, hi_); \
  k2##i = fmin(k2##i, hi2_); }

#define EVALS(qv, idxv) { \
  union { double d; u32 u[2]; } up_; \
  up_.u[0] = (idxv); \
  EVAL1(0, qv, up_) EVAL1(1, qv, up_) EVAL1(2, qv, up_) EVAL1(3, qv, up_) }

#define QSTORE(i) { \
  size_t q_ = (size_t)qbase + i * 256 + t; \
  pkey[(size_t)(chunk*3 + 0) * Mtot + q_] = k0##i; \
  pkey[(size_t)(chunk*3 + 1) * Mtot + q_] = k1##i; \
  pkey[(size_t)(chunk*3 + 2) * Mtot + q_] = k2##i; }

__global__ __launch_bounds__(256, 4) void knn_partial(
    const float* __restrict__ xyz1, const float* __restrict__ xyz2,
    double* __restrict__ pkey)
{
  __shared__ float4 s_q[SC];
  const int t     = threadIdx.x;
  const int chunk = blockIdx.x & (NCHUNK - 1);
  const int qb    = blockIdx.x >> 4;         // 0..63
  const int b     = qb >> 4;                 // batch (16 q-blocks per batch)
  const int qbase = qb << 10;                // 1024 queries per q-block

  {
    const float* src = xyz2 + ((size_t)b * Ss + chunk * SC + t) * 3;
    float x = src[0], y = src[1], z = src[2];
    s_q[t] = make_float4(-2.f * x, -2.f * y, -2.f * z, x*x + y*y + z*z);
  }
  QDECL(0) QDECL(1) QDECL(2) QDECL(3)
  QINIT(0) QINIT(1) QINIT(2) QINIT(3)
  QLOAD(0) QLOAD(1) QLOAD(2) QLOAD(3)
  __syncthreads();

  u32 sidx = (u32)(chunk * SC);
  for (int j = 0; j < SC; j += 4) {
    float4 qa  = s_q[j + 0];
    float4 qb_ = s_q[j + 1];
    float4 qc  = s_q[j + 2];
    float4 qd  = s_q[j + 3];
    EVALS(qa,  sidx)
    EVALS(qb_, sidx + 1)
    EVALS(qc,  sidx + 2)
    EVALS(qd,  sidx + 3)
    sidx += 4;
  }
  QSTORE(0) QSTORE(1) QSTORE(2) QSTORE(3)
}

// ---------------------------------------------------------------------------
// K2: merge 16 partials -> top-3, weights (n1 re-added), gather points2,
// concat -> Xb bf16. 1024 blocks x 256 threads; 64 queries per block.
// ---------------------------------------------------------------------------
__global__ __launch_bounds__(256) void knn_merge_interp(
    const float* __restrict__ xyz1,
    const float* __restrict__ points1, const float* __restrict__ points2,
    const double* __restrict__ pkey, u16* __restrict__ Xb)
{
  __shared__ int   s_i[64][3];
  __shared__ float s_w[64][3];
  const int t = threadIdx.x;
  const size_t qbase = (size_t)blockIdx.x * 64;
  const int b = (int)(qbase >> 14);

  if (t < 64) {
    size_t q = qbase + t;
    double k0 = pk(3.3e38f, 0xFFFFFFFFu);
    double k1 = k0, k2 = k0;
    #pragma unroll 4
    for (int c = 0; c < NCHUNK * 3; ++c) {
      double u = pkey[(size_t)c * Mtot + q];
      double hi  = fmax(k0, u);
      k0 = fmin(k0, u);
      double hi2 = fmax(k1, hi);
      k1 = fmin(k1, hi);
      k2 = fmin(k2, hi2);
    }
    const float* p = xyz1 + q * 3;
    float n1 = p[0]*p[0] + p[1]*p[1] + p[2]*p[2];
    float r0 = 1.f / (pk_key(k0) + n1 + 1e-8f);
    float r1 = 1.f / (pk_key(k1) + n1 + 1e-8f);
    float r2 = 1.f / (pk_key(k2) + n1 + 1e-8f);
    float rs = 1.f / (r0 + r1 + r2);
    s_i[t][0] = (int)pk_idx(k0);
    s_i[t][1] = (int)pk_idx(k1);
    s_i[t][2] = (int)pk_idx(k2);
    s_w[t][0] = r0 * rs; s_w[t][1] = r1 * rs; s_w[t][2] = r2 * rs;
  }
  __syncthreads();

  // points1 -> Xb[:, 0:128]
  const float* p1 = points1 + qbase * D1;
  u16* xr = Xb + qbase * INCH;
  #pragma unroll
  for (int k = 0; k < 8; ++k) {
    int i = k * 256 + t;
    int r = i >> 5, c4 = (i & 31) << 2;
    float4 v = *(const float4*)(p1 + (size_t)r * D1 + c4);
    us4 o = { f2bf(v.x), f2bf(v.y), f2bf(v.z), f2bf(v.w) };
    *(us4*)(xr + (size_t)r * INCH + c4) = o;
  }
  // interp -> Xb[:, 128:384]
  const float* p2 = points2 + (size_t)b * Ss * D2;
  const int sub = t >> 6, cg = (t & 63) << 2;
  #pragma unroll 2
  for (int pass = 0; pass < 16; ++pass) {
    int p = pass * 4 + sub;
    int i0 = s_i[p][0], i1 = s_i[p][1], i2 = s_i[p][2];
    float w0 = s_w[p][0], w1 = s_w[p][1], w2 = s_w[p][2];
    float4 f0 = *(const float4*)(p2 + (size_t)i0 * D2 + cg);
    float4 f1 = *(const float4*)(p2 + (size_t)i1 * D2 + cg);
    float4 f2 = *(const float4*)(p2 + (size_t)i2 * D2 + cg);
    float v0 = w0*f0.x + w1*f1.x + w2*f2.x;
    float v1 = w0*f0.y + w1*f1.y + w2*f2.y;
    float v2 = w0*f0.z + w1*f1.z + w2*f2.z;
    float v3 = w0*f0.w + w1*f1.w + w2*f2.w;
    us4 o = { f2bf(v0), f2bf(v1), f2bf(v2), f2bf(v3) };
    *(us4*)(xr + (size_t)p * INCH + D1 + cg) = o;
  }
}

// ---------------------------------------------------------------------------
// fp32 -> bf16 conversion of both weight matrices in one launch
// ---------------------------------------------------------------------------
__global__ __launch_bounds__(256) void cvt_weights_kernel(
    const float* __restrict__ w0s, u16* __restrict__ w0d,
    const float* __restrict__ w1s, u16* __restrict__ w1d)
{
  int i = blockIdx.x * 256 + threadIdx.x;
  const int n0 = C0 * INCH / 4;             // 24576
  const int n1 = C1 * C0 / 4;               // 8192
  if (i < n0) {
    float4 v = *(const float4*)(w0s + (size_t)i * 4);
    us4 o = { f2bf(v.x), f2bf(v.y), f2bf(v.z), f2bf(v.w) };
    *(us4*)(w0d + (size_t)i * 4) = o;
  } else if (i - n0 < n1) {
    int k = i - n0;
    float4 v = *(const float4*)(w1s + (size_t)k * 4);
    us4 o = { f2bf(v.x), f2bf(v.y), f2bf(v.z), f2bf(v.w) };
    *(us4*)(w1d + (size_t)k * 4) = o;
  }
}

// per-pair transform: relu(a*x+b) on two packed bf16
__device__ __forceinline__ u32 nr2(u32 two, float aL, float bL, float aH, float bH) {
  float lo = fmaxf(0.f, fmaf(bf2f((u16)(two & 0xffff)), aL, bL));
  float hi = fmaxf(0.f, fmaf(bf2f((u16)(two >> 16)),    aH, bH));
  return (u32)f2bf(lo) | ((u32)f2bf(hi) << 16);
}

// ---------------------------------------------------------------------------
// MFMA GEMM: out[M][NOUT] = X[M][K](bf16) * Wb[NOUT][K](bf16)^T + bias
// 128x128 tile, BK=64, 4 waves (2x2 of 64x64), 16x16x32 bf16 MFMA.
// ATRANS: A staged via registers with fused relu(a*x+b) channel transform
//   (ds_write to XOR-swizzled dest; same involution on read - rule 21).
// !ATRANS: A staged via global_load_lds with inverse-swizzled source.
// Epilogue: fused BN column stats (s, s^2) -> Spart/SQpart[512 slots][NOUT],
//   two row-half waves combined through LDS; fully deterministic.
// ---------------------------------------------------------------------------
template<int K, int NOUT, bool OUT_BF16, bool ATRANS>
__global__ __launch_bounds__(256) void gemm_mfma(
    const u16* __restrict__ X, const u16* __restrict__ Wb,
    const float* __restrict__ bias, const float* __restrict__ ABt,
    void* __restrict__ out, float* __restrict__ Spart, float* __restrict__ SQpart)
{
  __shared__ u16 ldsA[128 * 64];
  __shared__ u16 ldsB[128 * 64];
  const int t = threadIdx.x;
  const int w = t >> 6, lane = t & 63;
  const int m0 = blockIdx.y * 128, n0 = blockIdx.x * 128;
  const int wm = (w >> 1) * 64, wn = (w & 1) * 64;

  f32x4 acc[4][4];
  #pragma unroll
  for (int mi = 0; mi < 4; ++mi)
    #pragma unroll
    for (int ni = 0; ni < 4; ++ni)
      acc[mi][ni] = (f32x4){0.f, 0.f, 0.f, 0.f};

  // staging descriptors: chunk ci covers LDS bytes [(ci*256+t)*16, +16)
  const char* aS[4]; const char* bS[4];   // !ATRANS path (inverse-swz source)
  const u16* aRow[4]; char* aDst[4]; int abk[4];  // ATRANS path
  #pragma unroll
  for (int ci = 0; ci < 4; ++ci) {
    int d  = (ci * 256 + t) * 16;
    int r  = d >> 7;                 // row 0..127
    int cb = d & 127;                // byte-in-row
    int cbs = cb ^ ((r & 7) << 4);   // inverse swizzle on SOURCE
    bS[ci] = (const char*)(Wb + (size_t)(n0 + r) * K) + cbs;
    if constexpr (ATRANS) {
      aRow[ci] = X + (size_t)(m0 + r) * K + (cb >> 1);
      aDst[ci] = (char*)ldsA + (d ^ ((r & 7) << 4));
      abk[ci]  = cb >> 1;
    } else {
      aS[ci] = (const char*)(X + (size_t)(m0 + r) * K) + cbs;
    }
  }

  for (int kt = 0; kt < K / 64; ++kt) {
    __syncthreads();                 // previous tile consumed
    #pragma unroll
    for (int ci = 0; ci < 4; ++ci)
      gload16(bS[ci] + kt * 128, (char*)ldsB + (ci * 256 + w * 64) * 16);
    if constexpr (ATRANS) {
      #pragma unroll
      for (int ci = 0; ci < 4; ++ci) {
        uint4 xv = *(const uint4*)(aRow[ci] + kt * 64);
        int k0 = kt * 64 + abk[ci];
        float4 a0 = *(const float4*)(ABt + k0);
        float4 a1 = *(const float4*)(ABt + k0 + 4);
        float4 b0 = *(const float4*)(ABt + K + k0);
        float4 b1 = *(const float4*)(ABt + K + k0 + 4);
        uint4 ov;
        ov.x = nr2(xv.x, a0.x, b0.x, a0.y, b0.y);
        ov.y = nr2(xv.y, a0.z, b0.z, a0.w, b0.w);
        ov.z = nr2(xv.z, a1.x, b1.x, a1.y, b1.y);
        ov.w = nr2(xv.w, a1.z, b1.z, a1.w, b1.w);
        *(uint4*)aDst[ci] = ov;
      }
    } else {
      #pragma unroll
      for (int ci = 0; ci < 4; ++ci)
        gload16(aS[ci] + kt * 128, (char*)ldsA + (ci * 256 + w * 64) * 16);
    }
    __syncthreads();                 // compiler drains vmcnt+lgkmcnt
    #pragma unroll
    for (int ks = 0; ks < 2; ++ks) {
      bf16x8 a[4], bfr[4];
      const int ka = ks * 64 + ((lane >> 4) << 4);
      #pragma unroll
      for (int x = 0; x < 4; ++x) {
        int ra = wm + x * 16 + (lane & 15);
        a[x]   = *(const bf16x8*)((const char*)ldsA + ra * 128 + (ka ^ ((ra & 7) << 4)));
        int rb = wn + x * 16 + (lane & 15);
        bfr[x] = *(const bf16x8*)((const char*)ldsB + rb * 128 + (ka ^ ((rb & 7) << 4)));
      }
      #pragma unroll
      for (int mi = 0; mi < 4; ++mi)
        #pragma unroll
        for (int ni = 0; ni < 4; ++ni)
          acc[mi][ni] = __builtin_amdgcn_mfma_f32_16x16x32_bf16(
              a[mi], bfr[ni], acc[mi][ni], 0, 0, 0);
    }
  }

  // epilogue: C/D layout col=lane&15, row=(lane>>4)*4+reg (m89-verified)
  // + fused BN column stats (sum, sumsq of v = acc + bias, fp32 pre-rounding)
  __syncthreads();                   // LDS free -> reuse for stat combine
  float* redS  = (float*)ldsA;       // [128] local cols
  float* redSQ = redS + 128;
  const int col = lane & 15;
  const int rg  = (lane >> 4) << 2;
  float sv[4], qv[4];
  #pragma unroll
  for (int ni = 0; ni < 4; ++ni) {
    int c = n0 + wn + ni * 16 + col;
    float bb = bias[c];
    float s = 0.f, sq = 0.f;
    #pragma unroll
    for (int mi = 0; mi < 4; ++mi) {
      int rbase = m0 + wm + mi * 16 + rg;
      #pragma unroll
      for (int rr = 0; rr < 4; ++rr) {
        float v = acc[mi][ni][rr] + bb;
        s += v; sq = fmaf(v, v, sq);
        if constexpr (OUT_BF16)
          ((u16*)out)[(size_t)(rbase + rr) * NOUT + c] = f2bf(v);
        else
          ((float*)out)[(size_t)(rbase + rr) * NOUT + c] = v;
      }
    }
    s  += __shfl_xor(s, 16, 64);  s  += __shfl_xor(s, 32, 64);
    sq += __shfl_xor(sq, 16, 64); sq += __shfl_xor(sq, 32, 64);
    sv[ni] = s; qv[ni] = sq;
  }
  if ((w >> 1) == 1 && lane < 16) {
    #pragma unroll
    for (int ni = 0; ni < 4; ++ni) {
      redS [wn + ni * 16 + col] = sv[ni];
      redSQ[wn + ni * 16 + col] = qv[ni];
    }
  }
  __syncthreads();
  if ((w >> 1) == 0 && lane < 16) {
    #pragma unroll
    for (int ni = 0; ni < 4; ++ni) {
      int cl = wn + ni * 16 + col;
      Spart [(size_t)blockIdx.y * NOUT + n0 + cl] = sv[ni] + redS[cl];
      SQpart[(size_t)blockIdx.y * NOUT + n0 + cl] = qv[ni] + redSQ[cl];
    }
  }
}

// ---------------------------------------------------------------------------
// stats finish: grid = C blocks x 256 threads; reduce nslot partial slots,
// fold (mean, rstd, gamma, beta) -> per-channel (a, b).
// ---------------------------------------------------------------------------
__global__ __launch_bounds__(256) void stats_finish(
    const float* __restrict__ Spart, const float* __restrict__ SQpart,
    const float* __restrict__ gamma, const float* __restrict__ beta,
    float* __restrict__ AB, int nslot)
{
  const int C = gridDim.x, c = blockIdx.x, i = threadIdx.x;
  float s = 0.f, sq = 0.f;
  for (int k = i; k < nslot; k += 256) {
    s  += Spart [(size_t)k * C + c];
    sq += SQpart[(size_t)k * C + c];
  }
  #pragma unroll
  for (int d = 32; d; d >>= 1) {
    s  += __shfl_down(s, d, 64);
    sq += __shfl_down(sq, d, 64);
  }
  __shared__ float ls[4], lq[4];
  int w = i >> 6, lane = i & 63;
  if (lane == 0) { ls[w] = s; lq[w] = sq; }
  __syncthreads();
  if (i == 0) {
    s  = ls[0] + ls[1] + ls[2] + ls[3];
    sq = lq[0] + lq[1] + lq[2] + lq[3];
    const float inv = 1.0f / (float)Mtot;
    float mean = s * inv;
    float var  = fmaf(-mean, mean, sq * inv);
    float a = rsqrtf(var + 1e-5f) * gamma[c];
    AB[c]     = a;
    AB[C + c] = fmaf(-mean, a, beta[c]);
  }
}

__global__ __launch_bounds__(256) void norm_relu_f32(float* __restrict__ Y,
                                                     const float* __restrict__ AB)
{
  size_t g = (size_t)blockIdx.x * 256 + threadIdx.x;  // 4 f32 per thread
  float* p = Y + g * 4;
  int c0 = (int)((g * 4) & (C1 - 1));
  float4 v = *(const float4*)p;
  float4 a = *(const float4*)(AB + c0);
  float4 b = *(const float4*)(AB + C1 + c0);
  v.x = fmaxf(0.f, fmaf(v.x, a.x, b.x));
  v.y = fmaxf(0.f, fmaf(v.y, a.y, b.y));
  v.z = fmaxf(0.f, fmaf(v.z, a.z, b.z));
  v.w = fmaxf(0.f, fmaf(v.w, a.w, b.w));
  *(float4*)p = v;
}

// ---------------------------------------------------------------------------
extern "C" void kernel_launch(void* const* d_in, const int* in_sizes, int n_in,
                              void* d_out, int out_size, void* d_ws, size_t ws_size,
                              hipStream_t stream) {
  const float* xyz1    = (const float*)d_in[0];
  const float* xyz2    = (const float*)d_in[1];
  const float* points1 = (const float*)d_in[2];
  const float* points2 = (const float*)d_in[3];
  const float* w0  = (const float*)d_in[4];
  const float* b0  = (const float*)d_in[5];
  const float* g0  = (const float*)d_in[6];
  const float* be0 = (const float*)d_in[7];
  const float* w1  = (const float*)d_in[8];
  const float* b1  = (const float*)d_in[9];
  const float* g1  = (const float*)d_in[10];
  const float* be1 = (const float*)d_in[11];
  float* out = (float*)d_out;
  char* ws = (char*)d_ws;

  const size_t XB_OFF  = 0;                               // 50,331,648
  const size_t Y1_OFF  = (size_t)Mtot * INCH * 2;         // 33,554,432 (Y1)
  // K1 partials (f64, 25.2 MB) overlay Y1 region (dead before GEMM1 writes):
  const size_t PKEY_OFF = Y1_OFF;
  const size_t SP_OFF  = Y1_OFF + (size_t)Mtot * C0 * 2;  // 512x256 f32
  const size_t SQ_OFF  = SP_OFF + (size_t)512 * C0 * 4;
  const size_t AB0_OFF = SQ_OFF + (size_t)512 * C0 * 4;
  const size_t AB1_OFF = AB0_OFF + 2048;
  const size_t WB0_OFF = AB1_OFF + 2048;
  const size_t WB1_OFF = WB0_OFF + (size_t)C0 * INCH * 2;

  u16*    Xb   = (u16*)(ws + XB_OFF);
  u16*    Y1   = (u16*)(ws + Y1_OFF);
  double* pkey = (double*)(ws + PKEY_OFF);
  float*  SP   = (float*)(ws + SP_OFF);   // reused by both GEMMs (sequential)
  float*  SQ   = (float*)(ws + SQ_OFF);
  float*  AB0  = (float*)(ws + AB0_OFF);
  float*  AB1  = (float*)(ws + AB1_OFF);
  u16*    Wb0  = (u16*)(ws + WB0_OFF);
  u16*    Wb1  = (u16*)(ws + WB1_OFF);

  // 0) weights -> bf16
  cvt_weights_kernel<<<dim3(128), dim3(256), 0, stream>>>(w0, Wb0, w1, Wb1);
  // 1) KNN partial top-3 (exact fp32 key, n1 deferred; idx packed in f64)
  knn_partial<<<dim3(64 * NCHUNK), dim3(256), 0, stream>>>(xyz1, xyz2, pkey);
  // 2) merge + interpolate + concat -> Xb
  knn_merge_interp<<<dim3(Mtot / 64), dim3(256), 0, stream>>>(
      xyz1, points1, points2, pkey, Xb);
  // 3) GEMM1 + fused BN0 column stats: [M,384]x[384,256]^T -> Y1 raw bf16
  gemm_mfma<INCH, C0, true, false>
      <<<dim3(C0 / 128, Mtot / 128), dim3(256), 0, stream>>>(
      Xb, Wb0, b0, nullptr, (void*)Y1, SP, SQ);
  // 4) BN0 fold
  stats_finish<<<dim3(C0), dim3(256), 0, stream>>>(SP, SQ, g0, be0, AB0, 512);
  // 5) GEMM2 (A-staging applies relu(a*x+b)) + fused BN1 stats -> d_out raw f32
  gemm_mfma<C0, C1, false, true>
      <<<dim3(C1 / 128, Mtot / 128), dim3(256), 0, stream>>>(
      Y1, Wb1, b1, AB0, (void*)out, SP, SQ);
  // 6) BN1 fold
  stats_finish<<<dim3(C1), dim3(256), 0, stream>>>(SP, SQ, g1, be1, AB1, 512);
  // 7) normalize + relu d_out in place
  norm_relu_f32<<<dim3(Mtot * C1 / 4 / 256), dim3(256), 0, stream>>>(out, AB1);
}

// Round 12
// 184.983 us; speedup vs baseline: 1.3359x; 1.0010x over previous
//
#include <hip/hip_runtime.h>

#define Bz   4
#define Nn   16384
#define Ss   4096
#define D1   128
#define D2   256
#define INCH 384
#define C0   256
#define C1   128
#define Mtot 65536
#define NCHUNK 16
#define SC    256   // sources per chunk

typedef unsigned short u16;
typedef unsigned int u32;
typedef __attribute__((ext_vector_type(4))) float f32x4;
typedef __attribute__((ext_vector_type(8))) short bf16x8;
struct __align__(8) us4 { u16 x, y, z, w; };

__device__ __forceinline__ float bf2f(u16 u) {
  union { unsigned u; float f; } x; x.u = ((unsigned)u) << 16; return x.f;
}
__device__ __forceinline__ u16 f2bf(float f) {
  union { float f; unsigned u; } x; x.f = f;
  unsigned r = x.u + 0x7fffu + ((x.u >> 16) & 1u);
  return (u16)(r >> 16);
}
__device__ __forceinline__ u32 asu(float f) {
  union { float f; u32 u; } x; x.f = f; return x.u;
}
__device__ __forceinline__ u32 pk_idx(double d) {
  union { double d; u32 u[2]; } x; x.d = d; return x.u[0];
}
__device__ __forceinline__ float pk_key(double d) {
  union { double d; u32 u[2]; } x; x.d = d;
  union { u32 u; float f; } y; y.u = x.u[1]; return y.f;
}
__device__ __forceinline__ double pk(float key, u32 idx) {
  union { double d; u32 u[2]; } x;
  x.u[0] = idx; x.u[1] = asu(key);
  return x.d;
}
__device__ __forceinline__ void gload16(const void* g, void* l) {
  __builtin_amdgcn_global_load_lds(
      (const __attribute__((address_space(1))) unsigned*)g,
      (__attribute__((address_space(3))) unsigned*)l, 16, 0, 0);
}

// ---------------------------------------------------------------------------
// K1: partial top-3 per (query, source-chunk). Q=4 queries/thread.
// key = |s|^2 - 2<q,s>  (EXACT fp32; monotone in sq-dist, n1 added at merge).
// (key,idx) packed as f64 -> 5-op v_min/max_f64 sorting network (53.6
// cyc/eval measured r7/r11 -- best compiler-reachable exact insert).
// THIS ROUND'S EXPERIMENT: __launch_bounds__(256,3) raises the VGPR cap
// 36 -> ~168. r11's allocation (36 = exactly the live-state count, zero
// temp slack) suggests r3/r4-style move-churn; r4 showed cap 32->44 gave
// -13%. If dur drops ~30%: bloat confirmed. If unchanged: DP-pipe floor.
// Occupancy 4->3 blocks/CU resident (1024-block grid pipelines the rest).
// ---------------------------------------------------------------------------
#define QDECL(i) \
  float qx##i, qy##i, qz##i; \
  double k0##i, k1##i, k2##i;

#define QINIT(i) { \
  k0##i = pk(3.3e38f, 0xFFFFFFFFu); \
  k1##i = k0##i; k2##i = k0##i; }

#define QLOAD(i) { \
  const float* p_ = xyz1 + ((size_t)qbase + i * 256 + t) * 3; \
  qx##i = p_[0]; qy##i = p_[1]; qz##i = p_[2]; }

#define EVAL1(i, qv, up) { \
  up.u[1] = asu(fmaf(qx##i, qv.x, fmaf(qy##i, qv.y, fmaf(qz##i, qv.z, qv.w)))); \
  double u_ = up.d; \
  double hi_  = fmax(k0##i, u_); k0##i = fmin(k0##i, u_); \
  double hi2_ = fmax(k1##i, hi_); k1##i = fmin(k1##i, hi_); \
  k2##i = fmin(k2##i, hi2_); }

#define EVALS(qv, idxv) { \
  union { double d; u32 u[2]; } up_; \
  up_.u[0] = (idxv); \
  EVAL1(0, qv, up_) EVAL1(1, qv, up_) EVAL1(2, qv, up_) EVAL1(3, qv, up_) }

#define QSTORE(i) { \
  size_t q_ = (size_t)qbase + i * 256 + t; \
  pkey[(size_t)(chunk*3 + 0) * Mtot + q_] = k0##i; \
  pkey[(size_t)(chunk*3 + 1) * Mtot + q_] = k1##i; \
  pkey[(size_t)(chunk*3 + 2) * Mtot + q_] = k2##i; }

__global__ __launch_bounds__(256, 3) void knn_partial(
    const float* __restrict__ xyz1, const float* __restrict__ xyz2,
    double* __restrict__ pkey)
{
  __shared__ float4 s_q[SC];
  const int t     = threadIdx.x;
  const int chunk = blockIdx.x & (NCHUNK - 1);
  const int qb    = blockIdx.x >> 4;         // 0..63
  const int b     = qb >> 4;                 // batch (16 q-blocks per batch)
  const int qbase = qb << 10;                // 1024 queries per q-block

  {
    const float* src = xyz2 + ((size_t)b * Ss + chunk * SC + t) * 3;
    float x = src[0], y = src[1], z = src[2];
    s_q[t] = make_float4(-2.f * x, -2.f * y, -2.f * z, x*x + y*y + z*z);
  }
  QDECL(0) QDECL(1) QDECL(2) QDECL(3)
  QINIT(0) QINIT(1) QINIT(2) QINIT(3)
  QLOAD(0) QLOAD(1) QLOAD(2) QLOAD(3)
  __syncthreads();

  u32 sidx = (u32)(chunk * SC);
  for (int j = 0; j < SC; j += 4) {
    float4 qa  = s_q[j + 0];
    float4 qb_ = s_q[j + 1];
    float4 qc  = s_q[j + 2];
    float4 qd  = s_q[j + 3];
    EVALS(qa,  sidx)
    EVALS(qb_, sidx + 1)
    EVALS(qc,  sidx + 2)
    EVALS(qd,  sidx + 3)
    sidx += 4;
  }
  QSTORE(0) QSTORE(1) QSTORE(2) QSTORE(3)
}

// ---------------------------------------------------------------------------
// K2: merge 16 partials -> top-3, weights (n1 re-added), gather points2,
// concat -> Xb bf16. 1024 blocks x 256 threads; 64 queries per block.
// ---------------------------------------------------------------------------
__global__ __launch_bounds__(256) void knn_merge_interp(
    const float* __restrict__ xyz1,
    const float* __restrict__ points1, const float* __restrict__ points2,
    const double* __restrict__ pkey, u16* __restrict__ Xb)
{
  __shared__ int   s_i[64][3];
  __shared__ float s_w[64][3];
  const int t = threadIdx.x;
  const size_t qbase = (size_t)blockIdx.x * 64;
  const int b = (int)(qbase >> 14);

  if (t < 64) {
    size_t q = qbase + t;
    double k0 = pk(3.3e38f, 0xFFFFFFFFu);
    double k1 = k0, k2 = k0;
    #pragma unroll 4
    for (int c = 0; c < NCHUNK * 3; ++c) {
      double u = pkey[(size_t)c * Mtot + q];
      double hi  = fmax(k0, u);
      k0 = fmin(k0, u);
      double hi2 = fmax(k1, hi);
      k1 = fmin(k1, hi);
      k2 = fmin(k2, hi2);
    }
    const float* p = xyz1 + q * 3;
    float n1 = p[0]*p[0] + p[1]*p[1] + p[2]*p[2];
    float r0 = 1.f / (pk_key(k0) + n1 + 1e-8f);
    float r1 = 1.f / (pk_key(k1) + n1 + 1e-8f);
    float r2 = 1.f / (pk_key(k2) + n1 + 1e-8f);
    float rs = 1.f / (r0 + r1 + r2);
    s_i[t][0] = (int)pk_idx(k0);
    s_i[t][1] = (int)pk_idx(k1);
    s_i[t][2] = (int)pk_idx(k2);
    s_w[t][0] = r0 * rs; s_w[t][1] = r1 * rs; s_w[t][2] = r2 * rs;
  }
  __syncthreads();

  // points1 -> Xb[:, 0:128]
  const float* p1 = points1 + qbase * D1;
  u16* xr = Xb + qbase * INCH;
  #pragma unroll
  for (int k = 0; k < 8; ++k) {
    int i = k * 256 + t;
    int r = i >> 5, c4 = (i & 31) << 2;
    float4 v = *(const float4*)(p1 + (size_t)r * D1 + c4);
    us4 o = { f2bf(v.x), f2bf(v.y), f2bf(v.z), f2bf(v.w) };
    *(us4*)(xr + (size_t)r * INCH + c4) = o;
  }
  // interp -> Xb[:, 128:384]
  const float* p2 = points2 + (size_t)b * Ss * D2;
  const int sub = t >> 6, cg = (t & 63) << 2;
  #pragma unroll 2
  for (int pass = 0; pass < 16; ++pass) {
    int p = pass * 4 + sub;
    int i0 = s_i[p][0], i1 = s_i[p][1], i2 = s_i[p][2];
    float w0 = s_w[p][0], w1 = s_w[p][1], w2 = s_w[p][2];
    float4 f0 = *(const float4*)(p2 + (size_t)i0 * D2 + cg);
    float4 f1 = *(const float4*)(p2 + (size_t)i1 * D2 + cg);
    float4 f2 = *(const float4*)(p2 + (size_t)i2 * D2 + cg);
    float v0 = w0*f0.x + w1*f1.x + w2*f2.x;
    float v1 = w0*f0.y + w1*f1.y + w2*f2.y;
    float v2 = w0*f0.z + w1*f1.z + w2*f2.z;
    float v3 = w0*f0.w + w1*f1.w + w2*f2.w;
    us4 o = { f2bf(v0), f2bf(v1), f2bf(v2), f2bf(v3) };
    *(us4*)(xr + (size_t)p * INCH + D1 + cg) = o;
  }
}

// ---------------------------------------------------------------------------
// fp32 -> bf16 conversion of both weight matrices in one launch
// ---------------------------------------------------------------------------
__global__ __launch_bounds__(256) void cvt_weights_kernel(
    const float* __restrict__ w0s, u16* __restrict__ w0d,
    const float* __restrict__ w1s, u16* __restrict__ w1d)
{
  int i = blockIdx.x * 256 + threadIdx.x;
  const int n0 = C0 * INCH / 4;             // 24576
  const int n1 = C1 * C0 / 4;               // 8192
  if (i < n0) {
    float4 v = *(const float4*)(w0s + (size_t)i * 4);
    us4 o = { f2bf(v.x), f2bf(v.y), f2bf(v.z), f2bf(v.w) };
    *(us4*)(w0d + (size_t)i * 4) = o;
  } else if (i - n0 < n1) {
    int k = i - n0;
    float4 v = *(const float4*)(w1s + (size_t)k * 4);
    us4 o = { f2bf(v.x), f2bf(v.y), f2bf(v.z), f2bf(v.w) };
    *(us4*)(w1d + (size_t)k * 4) = o;
  }
}

// per-pair transform: relu(a*x+b) on two packed bf16
__device__ __forceinline__ u32 nr2(u32 two, float aL, float bL, float aH, float bH) {
  float lo = fmaxf(0.f, fmaf(bf2f((u16)(two & 0xffff)), aL, bL));
  float hi = fmaxf(0.f, fmaf(bf2f((u16)(two >> 16)),    aH, bH));
  return (u32)f2bf(lo) | ((u32)f2bf(hi) << 16);
}

// ---------------------------------------------------------------------------
// MFMA GEMM: out[M][NOUT] = X[M][K](bf16) * Wb[NOUT][K](bf16)^T + bias
// 128x128 tile, BK=64, 4 waves (2x2 of 64x64), 16x16x32 bf16 MFMA.
// ATRANS: A staged via registers with fused relu(a*x+b) channel transform
//   (ds_write to XOR-swizzled dest; same involution on read - rule 21).
// !ATRANS: A staged via global_load_lds with inverse-swizzled source.
// Epilogue: fused BN column stats (s, s^2) -> Spart/SQpart[512 slots][NOUT],
//   two row-half waves combined through LDS; fully deterministic.
// ---------------------------------------------------------------------------
template<int K, int NOUT, bool OUT_BF16, bool ATRANS>
__global__ __launch_bounds__(256) void gemm_mfma(
    const u16* __restrict__ X, const u16* __restrict__ Wb,
    const float* __restrict__ bias, const float* __restrict__ ABt,
    void* __restrict__ out, float* __restrict__ Spart, float* __restrict__ SQpart)
{
  __shared__ u16 ldsA[128 * 64];
  __shared__ u16 ldsB[128 * 64];
  const int t = threadIdx.x;
  const int w = t >> 6, lane = t & 63;
  const int m0 = blockIdx.y * 128, n0 = blockIdx.x * 128;
  const int wm = (w >> 1) * 64, wn = (w & 1) * 64;

  f32x4 acc[4][4];
  #pragma unroll
  for (int mi = 0; mi < 4; ++mi)
    #pragma unroll
    for (int ni = 0; ni < 4; ++ni)
      acc[mi][ni] = (f32x4){0.f, 0.f, 0.f, 0.f};

  // staging descriptors: chunk ci covers LDS bytes [(ci*256+t)*16, +16)
  const char* aS[4]; const char* bS[4];   // !ATRANS path (inverse-swz source)
  const u16* aRow[4]; char* aDst[4]; int abk[4];  // ATRANS path
  #pragma unroll
  for (int ci = 0; ci < 4; ++ci) {
    int d  = (ci * 256 + t) * 16;
    int r  = d >> 7;                 // row 0..127
    int cb = d & 127;                // byte-in-row
    int cbs = cb ^ ((r & 7) << 4);   // inverse swizzle on SOURCE
    bS[ci] = (const char*)(Wb + (size_t)(n0 + r) * K) + cbs;
    if constexpr (ATRANS) {
      aRow[ci] = X + (size_t)(m0 + r) * K + (cb >> 1);
      aDst[ci] = (char*)ldsA + (d ^ ((r & 7) << 4));
      abk[ci]  = cb >> 1;
    } else {
      aS[ci] = (const char*)(X + (size_t)(m0 + r) * K) + cbs;
    }
  }

  for (int kt = 0; kt < K / 64; ++kt) {
    __syncthreads();                 // previous tile consumed
    #pragma unroll
    for (int ci = 0; ci < 4; ++ci)
      gload16(bS[ci] + kt * 128, (char*)ldsB + (ci * 256 + w * 64) * 16);
    if constexpr (ATRANS) {
      #pragma unroll
      for (int ci = 0; ci < 4; ++ci) {
        uint4 xv = *(const uint4*)(aRow[ci] + kt * 64);
        int k0 = kt * 64 + abk[ci];
        float4 a0 = *(const float4*)(ABt + k0);
        float4 a1 = *(const float4*)(ABt + k0 + 4);
        float4 b0 = *(const float4*)(ABt + K + k0);
        float4 b1 = *(const float4*)(ABt + K + k0 + 4);
        uint4 ov;
        ov.x = nr2(xv.x, a0.x, b0.x, a0.y, b0.y);
        ov.y = nr2(xv.y, a0.z, b0.z, a0.w, b0.w);
        ov.z = nr2(xv.z, a1.x, b1.x, a1.y, b1.y);
        ov.w = nr2(xv.w, a1.z, b1.z, a1.w, b1.w);
        *(uint4*)aDst[ci] = ov;
      }
    } else {
      #pragma unroll
      for (int ci = 0; ci < 4; ++ci)
        gload16(aS[ci] + kt * 128, (char*)ldsA + (ci * 256 + w * 64) * 16);
    }
    __syncthreads();                 // compiler drains vmcnt+lgkmcnt
    #pragma unroll
    for (int ks = 0; ks < 2; ++ks) {
      bf16x8 a[4], bfr[4];
      const int ka = ks * 64 + ((lane >> 4) << 4);
      #pragma unroll
      for (int x = 0; x < 4; ++x) {
        int ra = wm + x * 16 + (lane & 15);
        a[x]   = *(const bf16x8*)((const char*)ldsA + ra * 128 + (ka ^ ((ra & 7) << 4)));
        int rb = wn + x * 16 + (lane & 15);
        bfr[x] = *(const bf16x8*)((const char*)ldsB + rb * 128 + (ka ^ ((rb & 7) << 4)));
      }
      #pragma unroll
      for (int mi = 0; mi < 4; ++mi)
        #pragma unroll
        for (int ni = 0; ni < 4; ++ni)
          acc[mi][ni] = __builtin_amdgcn_mfma_f32_16x16x32_bf16(
              a[mi], bfr[ni], acc[mi][ni], 0, 0, 0);
    }
  }

  // epilogue: C/D layout col=lane&15, row=(lane>>4)*4+reg (m89-verified)
  // + fused BN column stats (sum, sumsq of v = acc + bias, fp32 pre-rounding)
  __syncthreads();                   // LDS free -> reuse for stat combine
  float* redS  = (float*)ldsA;       // [128] local cols
  float* redSQ = redS + 128;
  const int col = lane & 15;
  const int rg  = (lane >> 4) << 2;
  float sv[4], qv[4];
  #pragma unroll
  for (int ni = 0; ni < 4; ++ni) {
    int c = n0 + wn + ni * 16 + col;
    float bb = bias[c];
    float s = 0.f, sq = 0.f;
    #pragma unroll
    for (int mi = 0; mi < 4; ++mi) {
      int rbase = m0 + wm + mi * 16 + rg;
      #pragma unroll
      for (int rr = 0; rr < 4; ++rr) {
        float v = acc[mi][ni][rr] + bb;
        s += v; sq = fmaf(v, v, sq);
        if constexpr (OUT_BF16)
          ((u16*)out)[(size_t)(rbase + rr) * NOUT + c] = f2bf(v);
        else
          ((float*)out)[(size_t)(rbase + rr) * NOUT + c] = v;
      }
    }
    s  += __shfl_xor(s, 16, 64);  s  += __shfl_xor(s, 32, 64);
    sq += __shfl_xor(sq, 16, 64); sq += __shfl_xor(sq, 32, 64);
    sv[ni] = s; qv[ni] = sq;
  }
  if ((w >> 1) == 1 && lane < 16) {
    #pragma unroll
    for (int ni = 0; ni < 4; ++ni) {
      redS [wn + ni * 16 + col] = sv[ni];
      redSQ[wn + ni * 16 + col] = qv[ni];
    }
  }
  __syncthreads();
  if ((w >> 1) == 0 && lane < 16) {
    #pragma unroll
    for (int ni = 0; ni < 4; ++ni) {
      int cl = wn + ni * 16 + col;
      Spart [(size_t)blockIdx.y * NOUT + n0 + cl] = sv[ni] + redS[cl];
      SQpart[(size_t)blockIdx.y * NOUT + n0 + cl] = qv[ni] + redSQ[cl];
    }
  }
}

// ---------------------------------------------------------------------------
// stats finish: grid = C blocks x 256 threads; reduce nslot partial slots,
// fold (mean, rstd, gamma, beta) -> per-channel (a, b).
// ---------------------------------------------------------------------------
__global__ __launch_bounds__(256) void stats_finish(
    const float* __restrict__ Spart, const float* __restrict__ SQpart,
    const float* __restrict__ gamma, const float* __restrict__ beta,
    float* __restrict__ AB, int nslot)
{
  const int C = gridDim.x, c = blockIdx.x, i = threadIdx.x;
  float s = 0.f, sq = 0.f;
  for (int k = i; k < nslot; k += 256) {
    s  += Spart [(size_t)k * C + c];
    sq += SQpart[(size_t)k * C + c];
  }
  #pragma unroll
  for (int d = 32; d; d >>= 1) {
    s  += __shfl_down(s, d, 64);
    sq += __shfl_down(sq, d, 64);
  }
  __shared__ float ls[4], lq[4];
  int w = i >> 6, lane = i & 63;
  if (lane == 0) { ls[w] = s; lq[w] = sq; }
  __syncthreads();
  if (i == 0) {
    s  = ls[0] + ls[1] + ls[2] + ls[3];
    sq = lq[0] + lq[1] + lq[2] + lq[3];
    const float inv = 1.0f / (float)Mtot;
    float mean = s * inv;
    float var  = fmaf(-mean, mean, sq * inv);
    float a = rsqrtf(var + 1e-5f) * gamma[c];
    AB[c]     = a;
    AB[C + c] = fmaf(-mean, a, beta[c]);
  }
}

__global__ __launch_bounds__(256) void norm_relu_f32(float* __restrict__ Y,
                                                     const float* __restrict__ AB)
{
  size_t g = (size_t)blockIdx.x * 256 + threadIdx.x;  // 4 f32 per thread
  float* p = Y + g * 4;
  int c0 = (int)((g * 4) & (C1 - 1));
  float4 v = *(const float4*)p;
  float4 a = *(const float4*)(AB + c0);
  float4 b = *(const float4*)(AB + C1 + c0);
  v.x = fmaxf(0.f, fmaf(v.x, a.x, b.x));
  v.y = fmaxf(0.f, fmaf(v.y, a.y, b.y));
  v.z = fmaxf(0.f, fmaf(v.z, a.z, b.z));
  v.w = fmaxf(0.f, fmaf(v.w, a.w, b.w));
  *(float4*)p = v;
}

// ---------------------------------------------------------------------------
extern "C" void kernel_launch(void* const* d_in, const int* in_sizes, int n_in,
                              void* d_out, int out_size, void* d_ws, size_t ws_size,
                              hipStream_t stream) {
  const float* xyz1    = (const float*)d_in[0];
  const float* xyz2    = (const float*)d_in[1];
  const float* points1 = (const float*)d_in[2];
  const float* points2 = (const float*)d_in[3];
  const float* w0  = (const float*)d_in[4];
  const float* b0  = (const float*)d_in[5];
  const float* g0  = (const float*)d_in[6];
  const float* be0 = (const float*)d_in[7];
  const float* w1  = (const float*)d_in[8];
  const float* b1  = (const float*)d_in[9];
  const float* g1  = (const float*)d_in[10];
  const float* be1 = (const float*)d_in[11];
  float* out = (float*)d_out;
  char* ws = (char*)d_ws;

  const size_t XB_OFF  = 0;                               // 50,331,648
  const size_t Y1_OFF  = (size_t)Mtot * INCH * 2;         // 33,554,432 (Y1)
  // K1 partials (f64, 25.2 MB) overlay Y1 region (dead before GEMM1 writes):
  const size_t PKEY_OFF = Y1_OFF;
  const size_t SP_OFF  = Y1_OFF + (size_t)Mtot * C0 * 2;  // 512x256 f32
  const size_t SQ_OFF  = SP_OFF + (size_t)512 * C0 * 4;
  const size_t AB0_OFF = SQ_OFF + (size_t)512 * C0 * 4;
  const size_t AB1_OFF = AB0_OFF + 2048;
  const size_t WB0_OFF = AB1_OFF + 2048;
  const size_t WB1_OFF = WB0_OFF + (size_t)C0 * INCH * 2;

  u16*    Xb   = (u16*)(ws + XB_OFF);
  u16*    Y1   = (u16*)(ws + Y1_OFF);
  double* pkey = (double*)(ws + PKEY_OFF);
  float*  SP   = (float*)(ws + SP_OFF);   // reused by both GEMMs (sequential)
  float*  SQ   = (float*)(ws + SQ_OFF);
  float*  AB0  = (float*)(ws + AB0_OFF);
  float*  AB1  = (float*)(ws + AB1_OFF);
  u16*    Wb0  = (u16*)(ws + WB0_OFF);
  u16*    Wb1  = (u16*)(ws + WB1_OFF);

  // 0) weights -> bf16
  cvt_weights_kernel<<<dim3(128), dim3(256), 0, stream>>>(w0, Wb0, w1, Wb1);
  // 1) KNN partial top-3 (exact fp32 key, n1 deferred; idx packed in f64)
  knn_partial<<<dim3(64 * NCHUNK), dim3(256), 0, stream>>>(xyz1, xyz2, pkey);
  // 2) merge + interpolate + concat -> Xb
  knn_merge_interp<<<dim3(Mtot / 64), dim3(256), 0, stream>>>(
      xyz1, points1, points2, pkey, Xb);
  // 3) GEMM1 + fused BN0 column stats: [M,384]x[384,256]^T -> Y1 raw bf16
  gemm_mfma<INCH, C0, true, false>
      <<<dim3(C0 / 128, Mtot / 128), dim3(256), 0, stream>>>(
      Xb, Wb0, b0, nullptr, (void*)Y1, SP, SQ);
  // 4) BN0 fold
  stats_finish<<<dim3(C0), dim3(256), 0, stream>>>(SP, SQ, g0, be0, AB0, 512);
  // 5) GEMM2 (A-staging applies relu(a*x+b)) + fused BN1 stats -> d_out raw f32
  gemm_mfma<C0, C1, false, true>
      <<<dim3(C1 / 128, Mtot / 128), dim3(256), 0, stream>>>(
      Y1, Wb1, b1, AB0, (void*)out, SP, SQ);
  // 6) BN1 fold
  stats_finish<<<dim3(C1), dim3(256), 0, stream>>>(SP, SQ, g1, be1, AB1, 512);
  // 7) normalize + relu d_out in place
  norm_relu_f32<<<dim3(Mtot * C1 / 4 / 256), dim3(256), 0, stream>>>(out, AB1);
}